// Round 3
// baseline (14976.305 us; speedup 1.0000x reference)
//
#include <hip/hip_runtime.h>
#include <cstdint>
#include <cstddef>

// ---------------------------------------------------------------------------
// 2-layer LSTM (T=2048, B=128, IN=88, H=200) + sigmoid FC head.
// Persistent pipelined kernel: 27 worker WGs (13 L0 unit-slices, 13 L1, 1 FC)
// + 229 ballast WGs (dependent-FMA spin) to hold DPM at boost clock.
// h exchanged via L3-coherent ring buffers + per-step release counters.
// R3: ballast WGs for clock recovery; pure poll loop (no in-loop spin).
// ---------------------------------------------------------------------------

#define TS    2048
#define BB    128
#define IN_D  88
#define HID   200
#define OUT_D 88
#define KX    96     // x segment padded to 3 K-tiles
#define KH    224    // h segment padded to 7 K-tiles
#define RING  4      // h buffer ring depth
#define FR    16     // flag ring slots
#define FSTR  32     // u32 per flag slot (128 B)

typedef __attribute__((ext_vector_type(8))) short short8;
typedef __attribute__((ext_vector_type(4))) float f32x4;

constexpr int NW0 = 13, NW1 = 13;
constexpr int NWORK = NW0 + NW1 + 1;   // 27
constexpr int NBAL  = 229;             // -> 256 WGs total, ~1/CU

__device__ inline unsigned short f2bf(float f){
  union{float f; unsigned u;} v; v.f = f;
  unsigned r = v.u + 0x7FFFu + ((v.u >> 16) & 1u);   // RNE
  return (unsigned short)(r >> 16);
}
__device__ inline float sigf(float x){ return 1.0f/(1.0f + __expf(-x)); }
__device__ inline float tanhf2(float x){ return 2.0f/(1.0f + __expf(-2.0f*x)) - 1.0f; }

__device__ inline unsigned ld_flag(const unsigned* p){
  return __hip_atomic_load(p, __ATOMIC_RELAXED, __HIP_MEMORY_SCOPE_AGENT);
}
__device__ inline void post1(unsigned* p){
  __hip_atomic_fetch_add(p, 1u, __ATOMIC_RELAXED, __HIP_MEMORY_SCOPE_AGENT);
}
__device__ inline unsigned* fsl(unsigned* base, int t){ return base + (size_t)(t & (FR-1))*FSTR; }
__device__ inline unsigned ftg(int t, int nw){ return (unsigned)((t/FR + 1)*nw); }

// combined poll: all pointers checked each iteration (1 round trip each).
__device__ inline void wait3(unsigned* p0, unsigned v0,
                             unsigned* p1, unsigned v1,
                             unsigned* p2, unsigned v2){
  if (!p0 && !p1 && !p2) return;
  int n = 0;
  for(;;){
    unsigned a0 = p0 ? ld_flag(p0) : 0u;
    unsigned a1 = p1 ? ld_flag(p1) : 0u;
    unsigned a2 = p2 ? ld_flag(p2) : 0u;
    bool ok = true;
    if (p0 && a0 < v0) ok = false;
    if (p1 && a1 < v1) ok = false;
    if (p2 && a2 < v2) ok = false;
    if (ok || ++n > 20000000) break;   // hang guard
  }
}

// coherent (L2-bypassing) 16B load of a B-fragment chunk
__device__ inline short8 loadB(const unsigned short* buf, int b, int k){
  const unsigned long long* p = (const unsigned long long*)(buf + b*KH + k);
  unsigned long long lo = __hip_atomic_load(p,   __ATOMIC_RELAXED, __HIP_MEMORY_SCOPE_AGENT);
  unsigned long long hi = __hip_atomic_load(p+1, __ATOMIC_RELAXED, __HIP_MEMORY_SCOPE_AGENT);
  union{ unsigned long long u[2]; short8 s; } v; v.u[0]=lo; v.u[1]=hi;
  return v.s;
}

__device__ inline void cvt_x(const float4* pa, const float4* pb, int q, short8* xf){
  #pragma unroll
  for (int kt = 0; kt < 3; ++kt){
    int k = kt*32 + q*8;
    short8 r = {0,0,0,0,0,0,0,0};
    if (k + 8 <= IN_D){
      r[0]=(short)f2bf(pa[kt].x); r[1]=(short)f2bf(pa[kt].y);
      r[2]=(short)f2bf(pa[kt].z); r[3]=(short)f2bf(pa[kt].w);
      r[4]=(short)f2bf(pb[kt].x); r[5]=(short)f2bf(pb[kt].y);
      r[6]=(short)f2bf(pb[kt].z); r[7]=(short)f2bf(pb[kt].w);
    }
    xf[kt] = r;
  }
}

// register-only dependent-FMA spin: keeps the GFX clock domain at boost.
__device__ void run_ballast(unsigned* done){
  float a = 1.0f, b = 1.1f, c = 1.2f, d = 1.3f;
  const float k = 1.0000001f;
  for (int it = 0; it < 40000; ++it){       // hard cap ~ hang guard
    #pragma unroll 16
    for (int i = 0; i < 1024; ++i){
      asm volatile("v_fmac_f32 %0, %4, %4\n"
                   "v_fmac_f32 %1, %4, %4\n"
                   "v_fmac_f32 %2, %4, %4\n"
                   "v_fmac_f32 %3, %4, %4"
                   : "+v"(a), "+v"(b), "+v"(c), "+v"(d) : "v"(k));
    }
    if (__hip_atomic_load(done, __ATOMIC_RELAXED, __HIP_MEMORY_SCOPE_AGENT)) break;
  }
  if (a == 0.12345f && b == c && c == d)    // never true; keeps spin alive
    done[1] = (unsigned)a;
}

template<int ROLE>
__device__ void run_role(int j0,
    const float* __restrict__ xin,
    const float* __restrict__ wi, const float* __restrict__ wh,
    const float* __restrict__ bi, const float* __restrict__ bh,
    float* __restrict__ out,
    unsigned short* h0buf, unsigned short* h1buf,
    unsigned* f0, unsigned* f1, unsigned* fF, unsigned* done,
    short* w_s, float* bias_s, unsigned short* hT)
{
  constexpr int STR  = (ROLE==0)?328:(ROLE==1?456:232); // K padded +8 (bank stagger)
  constexpr int ROWS = (ROLE==2)?96:64;
  constexpr int MT   = (ROLE==2)?6:4;
  const int tid = threadIdx.x;

  // ---- stage weights (fp32 global -> bf16 LDS), rows unit-major [unit][i,f,g,o]
  for (int idx = tid; idx < ROWS*STR; idx += 512){
    int r = idx / STR, k = idx - r*STR;
    float v = 0.f;
    if (ROLE == 2){
      if (r < OUT_D && k < HID) v = wi[r*HID + k];
    } else {
      int j = j0 + (r >> 2), g = r & 3;
      if (j < HID){
        int gr = g*HID + j;              // torch gate order i,f,g,o
        if (ROLE == 0){
          if (k < IN_D)                   v = wi[gr*IN_D + k];
          else if (k >= KX && k < KX+HID) v = wh[gr*HID + (k-KX)];
        } else {
          if (k < HID)                    v = wi[gr*HID + k];
          else if (k >= KH && k < KH+HID) v = wh[gr*HID + (k-KH)];
        }
      }
    }
    w_s[idx] = (short)f2bf(v);
  }
  for (int r = tid; r < ROWS; r += 512){
    float bv = 0.f;
    if (ROLE == 2){ if (r < OUT_D) bv = bi[r]; }
    else { int j = j0 + (r>>2), g = r&3; if (j < HID){ int gr = g*HID+j; bv = bi[gr] + bh[gr]; } }
    bias_s[r] = bv;
  }
  __syncthreads();

  const int lane = tid & 63;
  const int wv   = tid >> 6;     // 8 waves, one 16-batch N-tile each
  const int q    = lane >> 4;
  const int nn   = lane & 15;
  const int b    = wv*16 + nn;

  float c[MT], hl[MT];
  #pragma unroll
  for (int i=0;i<MT;i++){ c[i]=0.f; hl[i]=0.f; }

  short8 xf[3];
  float4 pa[3], pb[3];
  if (ROLE == 0){
    #pragma unroll
    for (int kt=0;kt<3;kt++){
      int k = kt*32 + q*8;
      if (k + 8 <= IN_D){
        const float* xp = xin + (size_t)b*IN_D + k;   // t=0
        pa[kt] = *(const float4*)xp; pb[kt] = *(const float4*)(xp + 4);
      }
    }
    cvt_x(pa, pb, q, xf);
  }

  for (int t = 0; t < TS; ++t){
    f32x4 acc[MT];
    #pragma unroll
    for (int mt=0; mt<MT; ++mt){
      #pragma unroll
      for (int r=0;r<4;r++) acc[mt][r] = bias_s[mt*16 + q*4 + r];
    }

    if (ROLE == 0){
      // x-projection (h-independent) BEFORE the wait
      #pragma unroll
      for (int kt=0; kt<3; ++kt){
        #pragma unroll
        for (int mt=0; mt<MT; ++mt){
          short8 af = *(const short8*)&w_s[(mt*16 + nn)*STR + kt*32 + q*8];
          acc[mt] = __builtin_amdgcn_mfma_f32_16x16x32_bf16(af, xf[kt], acc[mt], 0, 0, 0);
        }
      }
      // prefetch raw x for t+1 (latency hidden behind wait + recurrent part)
      if (t + 1 < TS){
        #pragma unroll
        for (int kt=0;kt<3;kt++){
          int k = kt*32 + q*8;
          if (k + 8 <= IN_D){
            const float* xp = xin + ((size_t)(t+1)*BB + b)*IN_D + k;
            pa[kt] = *(const float4*)xp; pb[kt] = *(const float4*)(xp + 4);
          }
        }
      }
      // wait: peers' h0[t-1]; ring guard f1[t-4]
      unsigned *p0=nullptr,*p1=nullptr; unsigned v0=0,v1=0;
      if (t >= 1){   p0 = fsl(f0, t-1);    v0 = ftg(t-1, NW0); }
      if (t >= RING){p1 = fsl(f1, t-RING); v1 = ftg(t-RING, NW1); }
      wait3(p0,v0,p1,v1,nullptr,0);
      // recurrent part
      const unsigned short* hs = h0buf + (size_t)((t-1)&(RING-1))*(BB*KH);
      short8 bfr[7];
      #pragma unroll
      for (int kt=0;kt<7;kt++) bfr[kt] = loadB(hs, b, kt*32 + q*8);
      #pragma unroll
      for (int kt=0;kt<7;kt++){
        #pragma unroll
        for (int mt=0; mt<MT; ++mt){
          short8 af = *(const short8*)&w_s[(mt*16 + nn)*STR + (3+kt)*32 + q*8];
          acc[mt] = __builtin_amdgcn_mfma_f32_16x16x32_bf16(af, bfr[kt], acc[mt], 0, 0, 0);
        }
      }
    } else if (ROLE == 1){
      // own-layer recurrence first
      unsigned *p0=nullptr,*p1=nullptr; unsigned v0=0,v1=0;
      if (t >= 1){   p0 = fsl(f1, t-1);    v0 = ftg(t-1, NW1); }
      if (t >= RING){p1 = fsl(fF, t-RING); v1 = ftg(t-RING, 1); }
      wait3(p0,v0,p1,v1,nullptr,0);
      const unsigned short* hs1 = h1buf + (size_t)((t-1)&(RING-1))*(BB*KH);
      short8 bfr[7];
      #pragma unroll
      for (int kt=0;kt<7;kt++) bfr[kt] = loadB(hs1, b, kt*32 + q*8);
      #pragma unroll
      for (int kt=0;kt<7;kt++){
        #pragma unroll
        for (int mt=0; mt<MT; ++mt){
          short8 af = *(const short8*)&w_s[(mt*16 + nn)*STR + (7+kt)*32 + q*8];
          acc[mt] = __builtin_amdgcn_mfma_f32_16x16x32_bf16(af, bfr[kt], acc[mt], 0, 0, 0);
        }
      }
      // then y0[t]
      wait3(fsl(f0,t), ftg(t,NW0), nullptr,0, nullptr,0);
      const unsigned short* hs0 = h0buf + (size_t)(t&(RING-1))*(BB*KH);
      #pragma unroll
      for (int kt=0;kt<7;kt++) bfr[kt] = loadB(hs0, b, kt*32 + q*8);
      #pragma unroll
      for (int kt=0;kt<7;kt++){
        #pragma unroll
        for (int mt=0; mt<MT; ++mt){
          short8 af = *(const short8*)&w_s[(mt*16 + nn)*STR + kt*32 + q*8];
          acc[mt] = __builtin_amdgcn_mfma_f32_16x16x32_bf16(af, bfr[kt], acc[mt], 0, 0, 0);
        }
      }
    } else {
      // FC head
      wait3(fsl(f1,t), ftg(t,NW1), nullptr,0, nullptr,0);
      const unsigned short* hs1 = h1buf + (size_t)(t&(RING-1))*(BB*KH);
      short8 bfr[7];
      #pragma unroll
      for (int kt=0;kt<7;kt++) bfr[kt] = loadB(hs1, b, kt*32 + q*8);
      #pragma unroll
      for (int kt=0;kt<7;kt++){
        #pragma unroll
        for (int mt=0; mt<MT; ++mt){
          short8 af = *(const short8*)&w_s[(mt*16 + nn)*STR + kt*32 + q*8];
          acc[mt] = __builtin_amdgcn_mfma_f32_16x16x32_bf16(af, bfr[kt], acc[mt], 0, 0, 0);
        }
      }
      __syncthreads();                 // all waves' h1 reads consumed
      if (tid == 0) post1(fsl(fF, t)); // release h1[t] early
      #pragma unroll
      for (int mt=0; mt<MT; ++mt){
        #pragma unroll
        for (int r=0;r<4;r++){
          int o = mt*16 + q*4 + r;
          if (o < OUT_D) out[((size_t)t*BB + b)*OUT_D + o] = sigf(acc[mt][r]);
        }
      }
      continue;
    }

    // ---- LSTM pointwise + h publish (roles 0/1) ----
    #pragma unroll
    for (int mt=0; mt<MT; ++mt){
      float ii = sigf(acc[mt][0]);
      float ff = sigf(acc[mt][1]);
      float gg = tanhf2(acc[mt][2]);
      float oo = sigf(acc[mt][3]);
      c[mt] = ff*c[mt] + ii*gg;
      float h = oo * tanhf2(c[mt]);
      hl[mt] = h;
      hT[b*16 + mt*4 + q] = f2bf(h);             // LDS transpose tile [b][unit_local]
    }
    __syncthreads();
    {                                            // coalesced coherent store of h slice
      int bb = tid >> 2, ch = tid & 3;
      if (j0 + ch*4 < HID){
        unsigned long long v = *(const unsigned long long*)&hT[bb*16 + ch*4];
        unsigned short* dst = (ROLE==0 ? h0buf : h1buf)
                            + (size_t)(t&(RING-1))*(BB*KH) + bb*KH + j0 + ch*4;
        __hip_atomic_store((unsigned long long*)dst, v,
                           __ATOMIC_RELAXED, __HIP_MEMORY_SCOPE_AGENT);
      }
    }
    asm volatile("s_waitcnt vmcnt(0)" ::: "memory");   // h stores at coherence point
    __syncthreads();
    if (tid == 0) post1(fsl(ROLE==0 ? f0 : f1, t));
    if (ROLE == 0) cvt_x(pa, pb, q, xf);               // convert prefetched x for t+1
  }

  if (ROLE == 2){
    if (tid == 0)
      __hip_atomic_store(done, 1u, __ATOMIC_RELAXED, __HIP_MEMORY_SCOPE_AGENT);
  } else {                                         // final hn / cn (fp32)
    size_t base = (size_t)TS*BB*OUT_D;
    float* hn = out + base + (size_t)ROLE*(BB*HID);
    float* cn = out + base + 2*(size_t)BB*HID + (size_t)ROLE*(BB*HID);
    #pragma unroll
    for (int mt=0; mt<MT; ++mt){
      int unit = j0 + mt*4 + q;
      if (unit < HID){
        hn[b*HID + unit] = hl[mt];
        cn[b*HID + unit] = c[mt];
      }
    }
  }
}

__global__ __launch_bounds__(512, 2) void lstm_net(
    const float* __restrict__ x,
    const float* __restrict__ wih0, const float* __restrict__ whh0,
    const float* __restrict__ bih0, const float* __restrict__ bhh0,
    const float* __restrict__ wih1, const float* __restrict__ whh1,
    const float* __restrict__ bih1, const float* __restrict__ bhh1,
    const float* __restrict__ wfc,  const float* __restrict__ bfc,
    float* __restrict__ out,
    unsigned short* h0buf, unsigned short* h1buf,
    unsigned* f0, unsigned* f1, unsigned* fF, unsigned* done)
{
  __shared__ short w_s[64*456];          // 58368 B (max over roles)
  __shared__ float bias_s[96];
  __shared__ unsigned short hT[128*16];  // h transpose tile
  int wg = blockIdx.x;
  if (wg >= NWORK){
    run_ballast(done);
  } else if (wg < NW0){
    run_role<0>(wg*16, x, wih0, whh0, bih0, bhh0, out, h0buf, h1buf, f0, f1, fF, done, w_s, bias_s, hT);
  } else if (wg < NW0+NW1){
    run_role<1>((wg-NW0)*16, x, wih1, whh1, bih1, bhh1, out, h0buf, h1buf, f0, f1, fF, done, w_s, bias_s, hT);
  } else {
    run_role<2>(0, x, wfc, nullptr, bfc, nullptr, out, h0buf, h1buf, f0, f1, fF, done, w_s, bias_s, hT);
  }
}

extern "C" void kernel_launch(void* const* d_in, const int* in_sizes, int n_in,
                              void* d_out, int out_size, void* d_ws, size_t ws_size,
                              hipStream_t stream) {
  const float* x    = (const float*)d_in[0];
  const float* wih0 = (const float*)d_in[1];
  const float* whh0 = (const float*)d_in[2];
  const float* bih0 = (const float*)d_in[3];
  const float* bhh0 = (const float*)d_in[4];
  const float* wih1 = (const float*)d_in[5];
  const float* whh1 = (const float*)d_in[6];
  const float* bih1 = (const float*)d_in[7];
  const float* bhh1 = (const float*)d_in[8];
  const float* wfc  = (const float*)d_in[9];
  const float* bfc  = (const float*)d_in[10];
  float* out = (float*)d_out;

  char* ws = (char*)d_ws;
  const size_t HSZ = (size_t)RING * BB * KH * 2;       // 229376 B per layer ring
  unsigned short* h0 = (unsigned short*)(ws + 0);
  unsigned short* h1 = (unsigned short*)(ws + HSZ);
  unsigned* f0   = (unsigned*)(ws + 2*HSZ);            // FR*FSTR u32 = 2048 B each
  unsigned* f1   = (unsigned*)(ws + 2*HSZ + 2048);
  unsigned* fF   = (unsigned*)(ws + 2*HSZ + 4096);
  unsigned* done = (unsigned*)(ws + 2*HSZ + 6144);     // 128 B

  hipMemsetAsync(d_ws, 0, 2*HSZ + 6144 + 128, stream); // zero h rings + flags + done
  hipLaunchKernelGGL(lstm_net, dim3(NWORK + NBAL), dim3(512), 0, stream,
      x, wih0, whh0, bih0, bhh0, wih1, whh1, bih1, bhh1, wfc, bfc,
      out, h0, h1, f0, f1, fF, done);
}

// Round 4
// 14545.564 us; speedup vs baseline: 1.0296x; 1.0296x over previous
//
#include <hip/hip_runtime.h>
#include <cstdint>
#include <cstddef>

// ---------------------------------------------------------------------------
// 2-layer LSTM (T=2048, B=128, IN=88, H=200) + sigmoid FC head.
// Persistent pipelined kernel: 27 WGs (13 L0 unit-slices, 13 L1, 1 FC).
// h exchanged via L3-coherent ring buffers + per-step release counters.
// R4: poll-flood fix — one polling wave per WG (lane-uniform load + s_sleep
// backoff + barrier release), flag arrays split per consumer class so each
// 128B flag line has <=13 pollers. Ballast removed (R3 proved clocks are
// not the limiter; chain lives in the fabric/L3 domain).
// ---------------------------------------------------------------------------

#define TS    2048
#define BB    128
#define IN_D  88
#define HID   200
#define OUT_D 88
#define KX    96     // x segment padded to 3 K-tiles
#define KH    224    // h segment padded to 7 K-tiles
#define RING  4      // h buffer ring depth
#define FR    16     // flag ring slots
#define FSTR  32     // u32 per flag slot (128 B)

typedef __attribute__((ext_vector_type(8))) short short8;
typedef __attribute__((ext_vector_type(4))) float f32x4;

constexpr int NW0 = 13, NW1 = 13;
constexpr int NWORK = NW0 + NW1 + 1;   // 27

__device__ inline unsigned short f2bf(float f){
  union{float f; unsigned u;} v; v.f = f;
  unsigned r = v.u + 0x7FFFu + ((v.u >> 16) & 1u);   // RNE
  return (unsigned short)(r >> 16);
}
__device__ inline float sigf(float x){ return 1.0f/(1.0f + __expf(-x)); }
__device__ inline float tanhf2(float x){ return 2.0f/(1.0f + __expf(-2.0f*x)) - 1.0f; }

__device__ inline unsigned ld_flag(const unsigned* p){
  return __hip_atomic_load(p, __ATOMIC_RELAXED, __HIP_MEMORY_SCOPE_AGENT);
}
__device__ inline void post1(unsigned* p){
  __hip_atomic_fetch_add(p, 1u, __ATOMIC_RELAXED, __HIP_MEMORY_SCOPE_AGENT);
}
__device__ inline unsigned* fsl(unsigned* base, int t){ return base + (size_t)(t & (FR-1))*FSTR; }
__device__ inline unsigned ftg(int t, int nw){ return (unsigned)((t/FR + 1)*nw); }

// WG-level wait: only wave 0 polls (lane-uniform address -> 1 request/poll),
// with s_sleep backoff; __syncthreads releases the other waves.
__device__ inline void wg_wait2(int tid, unsigned* p0, unsigned v0,
                                unsigned* p1, unsigned v1){
  if (tid < 64 && (p0 || p1)){
    int n = 0;
    for(;;){
      unsigned a0 = p0 ? ld_flag(p0) : 0xFFFFFFFFu;
      unsigned a1 = p1 ? ld_flag(p1) : 0xFFFFFFFFu;
      bool ok = true;
      if (p0 && a0 < v0) ok = false;
      if (p1 && a1 < v1) ok = false;
      if (ok || ++n > 4000) break;      // hang guard: fail loud, don't hang
      __builtin_amdgcn_s_sleep(1);
    }
  }
  __syncthreads();
}

// coherent (L2-bypassing) 16B load of a B-fragment chunk
__device__ inline short8 loadB(const unsigned short* buf, int b, int k){
  const unsigned long long* p = (const unsigned long long*)(buf + b*KH + k);
  unsigned long long lo = __hip_atomic_load(p,   __ATOMIC_RELAXED, __HIP_MEMORY_SCOPE_AGENT);
  unsigned long long hi = __hip_atomic_load(p+1, __ATOMIC_RELAXED, __HIP_MEMORY_SCOPE_AGENT);
  union{ unsigned long long u[2]; short8 s; } v; v.u[0]=lo; v.u[1]=hi;
  return v.s;
}

__device__ inline void cvt_x(const float4* pa, const float4* pb, int q, short8* xf){
  #pragma unroll
  for (int kt = 0; kt < 3; ++kt){
    int k = kt*32 + q*8;
    short8 r = {0,0,0,0,0,0,0,0};
    if (k + 8 <= IN_D){
      r[0]=(short)f2bf(pa[kt].x); r[1]=(short)f2bf(pa[kt].y);
      r[2]=(short)f2bf(pa[kt].z); r[3]=(short)f2bf(pa[kt].w);
      r[4]=(short)f2bf(pb[kt].x); r[5]=(short)f2bf(pb[kt].y);
      r[6]=(short)f2bf(pb[kt].z); r[7]=(short)f2bf(pb[kt].w);
    }
    xf[kt] = r;
  }
}

template<int ROLE>
__device__ void run_role(int j0,
    const float* __restrict__ xin,
    const float* __restrict__ wi, const float* __restrict__ wh,
    const float* __restrict__ bi, const float* __restrict__ bh,
    float* __restrict__ out,
    unsigned short* h0buf, unsigned short* h1buf,
    unsigned* f0p, unsigned* f0c, unsigned* f1p, unsigned* f1c,
    unsigned* f1g, unsigned* fFg,
    short* w_s, float* bias_s, unsigned short* hT)
{
  constexpr int STR  = (ROLE==0)?328:(ROLE==1?456:232); // K padded +8 (bank stagger)
  constexpr int ROWS = (ROLE==2)?96:64;
  constexpr int MT   = (ROLE==2)?6:4;
  const int tid = threadIdx.x;

  // ---- stage weights (fp32 global -> bf16 LDS), rows unit-major [unit][i,f,g,o]
  for (int idx = tid; idx < ROWS*STR; idx += 512){
    int r = idx / STR, k = idx - r*STR;
    float v = 0.f;
    if (ROLE == 2){
      if (r < OUT_D && k < HID) v = wi[r*HID + k];
    } else {
      int j = j0 + (r >> 2), g = r & 3;
      if (j < HID){
        int gr = g*HID + j;              // torch gate order i,f,g,o
        if (ROLE == 0){
          if (k < IN_D)                   v = wi[gr*IN_D + k];
          else if (k >= KX && k < KX+HID) v = wh[gr*HID + (k-KX)];
        } else {
          if (k < HID)                    v = wi[gr*HID + k];
          else if (k >= KH && k < KH+HID) v = wh[gr*HID + (k-KH)];
        }
      }
    }
    w_s[idx] = (short)f2bf(v);
  }
  for (int r = tid; r < ROWS; r += 512){
    float bv = 0.f;
    if (ROLE == 2){ if (r < OUT_D) bv = bi[r]; }
    else { int j = j0 + (r>>2), g = r&3; if (j < HID){ int gr = g*HID+j; bv = bi[gr] + bh[gr]; } }
    bias_s[r] = bv;
  }
  __syncthreads();

  const int lane = tid & 63;
  const int wv   = tid >> 6;     // 8 waves, one 16-batch N-tile each
  const int q    = lane >> 4;
  const int nn   = lane & 15;
  const int b    = wv*16 + nn;

  float c[MT], hl[MT];
  #pragma unroll
  for (int i=0;i<MT;i++){ c[i]=0.f; hl[i]=0.f; }

  short8 xf[3];
  float4 pa[3], pb[3];
  if (ROLE == 0){
    #pragma unroll
    for (int kt=0;kt<3;kt++){
      int k = kt*32 + q*8;
      if (k + 8 <= IN_D){
        const float* xp = xin + (size_t)b*IN_D + k;   // t=0
        pa[kt] = *(const float4*)xp; pb[kt] = *(const float4*)(xp + 4);
      }
    }
    cvt_x(pa, pb, q, xf);
  }

  for (int t = 0; t < TS; ++t){
    f32x4 acc[MT];
    #pragma unroll
    for (int mt=0; mt<MT; ++mt){
      #pragma unroll
      for (int r=0;r<4;r++) acc[mt][r] = bias_s[mt*16 + q*4 + r];
    }

    if (ROLE == 0){
      // x-projection (h-independent) BEFORE the wait
      #pragma unroll
      for (int kt=0; kt<3; ++kt){
        #pragma unroll
        for (int mt=0; mt<MT; ++mt){
          short8 af = *(const short8*)&w_s[(mt*16 + nn)*STR + kt*32 + q*8];
          acc[mt] = __builtin_amdgcn_mfma_f32_16x16x32_bf16(af, xf[kt], acc[mt], 0, 0, 0);
        }
      }
      // prefetch raw x for t+1 (latency hidden behind wait + recurrent part)
      if (t + 1 < TS){
        #pragma unroll
        for (int kt=0;kt<3;kt++){
          int k = kt*32 + q*8;
          if (k + 8 <= IN_D){
            const float* xp = xin + ((size_t)(t+1)*BB + b)*IN_D + k;
            pa[kt] = *(const float4*)xp; pb[kt] = *(const float4*)(xp + 4);
          }
        }
      }
      // wait: peers' h0[t-1] (f0p); ring guard f1g[t-RING]
      unsigned *p0=nullptr,*p1=nullptr; unsigned v0=0,v1=0;
      if (t >= 1){   p0 = fsl(f0p, t-1);    v0 = ftg(t-1, NW0); }
      if (t >= RING){p1 = fsl(f1g, t-RING); v1 = ftg(t-RING, NW1); }
      wg_wait2(tid, p0, v0, p1, v1);
      // recurrent part
      const unsigned short* hs = h0buf + (size_t)((t-1)&(RING-1))*(BB*KH);
      short8 bfr[7];
      #pragma unroll
      for (int kt=0;kt<7;kt++) bfr[kt] = loadB(hs, b, kt*32 + q*8);
      #pragma unroll
      for (int kt=0;kt<7;kt++){
        #pragma unroll
        for (int mt=0; mt<MT; ++mt){
          short8 af = *(const short8*)&w_s[(mt*16 + nn)*STR + (3+kt)*32 + q*8];
          acc[mt] = __builtin_amdgcn_mfma_f32_16x16x32_bf16(af, bfr[kt], acc[mt], 0, 0, 0);
        }
      }
    } else if (ROLE == 1){
      // own-layer recurrence first: h1[t-1] (f1p); ring guard fFg[t-RING]
      unsigned *p0=nullptr,*p1=nullptr; unsigned v0=0,v1=0;
      if (t >= 1){   p0 = fsl(f1p, t-1);    v0 = ftg(t-1, NW1); }
      if (t >= RING){p1 = fsl(fFg, t-RING); v1 = ftg(t-RING, 1); }
      wg_wait2(tid, p0, v0, p1, v1);
      const unsigned short* hs1 = h1buf + (size_t)((t-1)&(RING-1))*(BB*KH);
      short8 bfr[7];
      #pragma unroll
      for (int kt=0;kt<7;kt++) bfr[kt] = loadB(hs1, b, kt*32 + q*8);
      #pragma unroll
      for (int kt=0;kt<7;kt++){
        #pragma unroll
        for (int mt=0; mt<MT; ++mt){
          short8 af = *(const short8*)&w_s[(mt*16 + nn)*STR + (7+kt)*32 + q*8];
          acc[mt] = __builtin_amdgcn_mfma_f32_16x16x32_bf16(af, bfr[kt], acc[mt], 0, 0, 0);
        }
      }
      // then y0[t] (f0c)
      wg_wait2(tid, fsl(f0c, t), ftg(t, NW0), nullptr, 0);
      const unsigned short* hs0 = h0buf + (size_t)(t&(RING-1))*(BB*KH);
      #pragma unroll
      for (int kt=0;kt<7;kt++) bfr[kt] = loadB(hs0, b, kt*32 + q*8);
      #pragma unroll
      for (int kt=0;kt<7;kt++){
        #pragma unroll
        for (int mt=0; mt<MT; ++mt){
          short8 af = *(const short8*)&w_s[(mt*16 + nn)*STR + kt*32 + q*8];
          acc[mt] = __builtin_amdgcn_mfma_f32_16x16x32_bf16(af, bfr[kt], acc[mt], 0, 0, 0);
        }
      }
    } else {
      // FC head: h1[t] (f1c)
      wg_wait2(tid, fsl(f1c, t), ftg(t, NW1), nullptr, 0);
      const unsigned short* hs1 = h1buf + (size_t)(t&(RING-1))*(BB*KH);
      short8 bfr[7];
      #pragma unroll
      for (int kt=0;kt<7;kt++) bfr[kt] = loadB(hs1, b, kt*32 + q*8);
      #pragma unroll
      for (int kt=0;kt<7;kt++){
        #pragma unroll
        for (int mt=0; mt<MT; ++mt){
          short8 af = *(const short8*)&w_s[(mt*16 + nn)*STR + kt*32 + q*8];
          acc[mt] = __builtin_amdgcn_mfma_f32_16x16x32_bf16(af, bfr[kt], acc[mt], 0, 0, 0);
        }
      }
      __syncthreads();                  // all waves' h1 reads consumed
      if (tid == 0) post1(fsl(fFg, t)); // release h1[t] slot
      #pragma unroll
      for (int mt=0; mt<MT; ++mt){
        #pragma unroll
        for (int r=0;r<4;r++){
          int o = mt*16 + q*4 + r;
          if (o < OUT_D) out[((size_t)t*BB + b)*OUT_D + o] = sigf(acc[mt][r]);
        }
      }
      continue;
    }

    // ---- LSTM pointwise + h publish (roles 0/1) ----
    #pragma unroll
    for (int mt=0; mt<MT; ++mt){
      float ii = sigf(acc[mt][0]);
      float ff = sigf(acc[mt][1]);
      float gg = tanhf2(acc[mt][2]);
      float oo = sigf(acc[mt][3]);
      c[mt] = ff*c[mt] + ii*gg;
      float h = oo * tanhf2(c[mt]);
      hl[mt] = h;
      hT[b*16 + mt*4 + q] = f2bf(h);             // LDS transpose tile [b][unit_local]
    }
    __syncthreads();
    {                                            // coalesced coherent store of h slice
      int bb = tid >> 2, ch = tid & 3;
      if (j0 + ch*4 < HID){
        unsigned long long v = *(const unsigned long long*)&hT[bb*16 + ch*4];
        unsigned short* dst = (ROLE==0 ? h0buf : h1buf)
                            + (size_t)(t&(RING-1))*(BB*KH) + bb*KH + j0 + ch*4;
        __hip_atomic_store((unsigned long long*)dst, v,
                           __ATOMIC_RELAXED, __HIP_MEMORY_SCOPE_AGENT);
      }
    }
    asm volatile("s_waitcnt vmcnt(0)" ::: "memory");   // h stores at coherence point
    __syncthreads();
    if (tid == 0){
      if (ROLE == 0){ post1(fsl(f0p, t)); post1(fsl(f0c, t)); }
      else          { post1(fsl(f1p, t)); post1(fsl(f1c, t)); post1(fsl(f1g, t)); }
    }
    if (ROLE == 0) cvt_x(pa, pb, q, xf);               // convert prefetched x for t+1
  }

  if (ROLE < 2){                                   // final hn / cn (fp32)
    size_t base = (size_t)TS*BB*OUT_D;
    float* hn = out + base + (size_t)ROLE*(BB*HID);
    float* cn = out + base + 2*(size_t)BB*HID + (size_t)ROLE*(BB*HID);
    #pragma unroll
    for (int mt=0; mt<MT; ++mt){
      int unit = j0 + mt*4 + q;
      if (unit < HID){
        hn[b*HID + unit] = hl[mt];
        cn[b*HID + unit] = c[mt];
      }
    }
  }
}

__global__ __launch_bounds__(512, 2) void lstm_net(
    const float* __restrict__ x,
    const float* __restrict__ wih0, const float* __restrict__ whh0,
    const float* __restrict__ bih0, const float* __restrict__ bhh0,
    const float* __restrict__ wih1, const float* __restrict__ whh1,
    const float* __restrict__ bih1, const float* __restrict__ bhh1,
    const float* __restrict__ wfc,  const float* __restrict__ bfc,
    float* __restrict__ out,
    unsigned short* h0buf, unsigned short* h1buf,
    unsigned* f0p, unsigned* f0c, unsigned* f1p, unsigned* f1c,
    unsigned* f1g, unsigned* fFg)
{
  __shared__ short w_s[64*456];          // 58368 B (max over roles)
  __shared__ float bias_s[96];
  __shared__ unsigned short hT[128*16];  // h transpose tile
  int wg = blockIdx.x;
  if (wg < NW0){
    run_role<0>(wg*16, x, wih0, whh0, bih0, bhh0, out, h0buf, h1buf,
                f0p, f0c, f1p, f1c, f1g, fFg, w_s, bias_s, hT);
  } else if (wg < NW0+NW1){
    run_role<1>((wg-NW0)*16, x, wih1, whh1, bih1, bhh1, out, h0buf, h1buf,
                f0p, f0c, f1p, f1c, f1g, fFg, w_s, bias_s, hT);
  } else {
    run_role<2>(0, x, wfc, nullptr, bfc, nullptr, out, h0buf, h1buf,
                f0p, f0c, f1p, f1c, f1g, fFg, w_s, bias_s, hT);
  }
}

extern "C" void kernel_launch(void* const* d_in, const int* in_sizes, int n_in,
                              void* d_out, int out_size, void* d_ws, size_t ws_size,
                              hipStream_t stream) {
  const float* x    = (const float*)d_in[0];
  const float* wih0 = (const float*)d_in[1];
  const float* whh0 = (const float*)d_in[2];
  const float* bih0 = (const float*)d_in[3];
  const float* bhh0 = (const float*)d_in[4];
  const float* wih1 = (const float*)d_in[5];
  const float* whh1 = (const float*)d_in[6];
  const float* bih1 = (const float*)d_in[7];
  const float* bhh1 = (const float*)d_in[8];
  const float* wfc  = (const float*)d_in[9];
  const float* bfc  = (const float*)d_in[10];
  float* out = (float*)d_out;

  char* ws = (char*)d_ws;
  const size_t HSZ = (size_t)RING * BB * KH * 2;       // 229376 B per layer ring
  const size_t FSZ = (size_t)FR * FSTR * 4;            // 2048 B per flag array
  unsigned short* h0 = (unsigned short*)(ws + 0);
  unsigned short* h1 = (unsigned short*)(ws + HSZ);
  unsigned* f0p = (unsigned*)(ws + 2*HSZ + 0*FSZ);
  unsigned* f0c = (unsigned*)(ws + 2*HSZ + 1*FSZ);
  unsigned* f1p = (unsigned*)(ws + 2*HSZ + 2*FSZ);
  unsigned* f1c = (unsigned*)(ws + 2*HSZ + 3*FSZ);
  unsigned* f1g = (unsigned*)(ws + 2*HSZ + 4*FSZ);
  unsigned* fFg = (unsigned*)(ws + 2*HSZ + 5*FSZ);

  hipMemsetAsync(d_ws, 0, 2*HSZ + 6*FSZ, stream);      // zero h rings + flags
  hipLaunchKernelGGL(lstm_net, dim3(NWORK), dim3(512), 0, stream,
      x, wih0, whh0, bih0, bhh0, wih1, whh1, bih1, bhh1, wfc, bfc,
      out, h0, h1, f0p, f0c, f1p, f1c, f1g, fFg);
}